// Round 2
// baseline (418.837 us; speedup 1.0000x reference)
//
#include <hip/hip_runtime.h>

// ---------------------------------------------------------------------------
// Multi-gate MoE: x[16384,1024] -> experts (2x Linear+ReLU, E=8) -> 4 gates.
// GEMMs use a 256x256 tile, 8-wave, 4-phase-per-K-tile pipelined schedule:
//   T2 LDS granule swizzle (conflict-free ds_read_b128, pre-swizzled gsrc)
//   T3/T4 counted vmcnt(8) at K-tile boundaries (never 0 in main loop)
//   T5 s_setprio(1) around MFMA clusters
//   T1 bijective XCD blockIdx swizzle
// ---------------------------------------------------------------------------

typedef __attribute__((ext_vector_type(8))) __bf16 bf16x8;
typedef __attribute__((ext_vector_type(4))) float f32x4;
typedef __attribute__((ext_vector_type(8))) unsigned short u16x8;

__device__ __forceinline__ float bf2f(unsigned short u) {
  union { unsigned int i; float f; } x;
  x.i = ((unsigned int)u) << 16;
  return x.f;
}

__device__ __forceinline__ unsigned short f2bf(float f) {
  union { float f; unsigned int i; } x;
  x.f = f;
  unsigned int r = x.i + 0x7FFFu + ((x.i >> 16) & 1u);  // round-to-nearest-even
  return (unsigned short)(r >> 16);
}

__device__ __forceinline__ void gload_lds16(const unsigned short* g, unsigned short* l) {
  __builtin_amdgcn_global_load_lds(
      (const __attribute__((address_space(1))) void*)g,
      (__attribute__((address_space(3))) void*)l, 16, 0, 0);
}

// Stage one 128x64 bf16 half-tile (16 KB) into an LDS region, linear dest,
// inverse-swizzled global source (granule ^= row&7). 2 loads/thread.
__device__ __forceinline__ void stage_half(const unsigned short* gbase, int gld,
                                           unsigned short* region, int wid, int lane) {
#pragma unroll
  for (int c = 0; c < 2; ++c) {
    int d = ((wid * 64 + lane) << 4) + (c << 13);   // byte offset in region
    int row = d >> 7;                               // 128 B per row
    int gr = ((d >> 4) & 7) ^ (row & 7);            // logical 16B-granule
    gload_lds16(gbase + (size_t)row * gld + (gr << 3),
                region + ((wid << 9) + (c << 12))); // wave-uniform dest (elements)
  }
}

// Swizzled fragment read: logical (row, col=kk*32+lhi*8) -> phys byte.
__device__ __forceinline__ bf16x8 frag_ld(const unsigned short* region, int row, int kk, int lhi) {
  int byte = (row << 7) + (kk << 6) + (lhi << 4);
  byte ^= (row & 7) << 4;
  return *(const bf16x8*)((const char*)region + byte);
}

// --------------------------- fp32 -> bf16 convert ---------------------------
__global__ void cvt_k(const float* __restrict__ in, unsigned short* __restrict__ out, int n4) {
  int i = blockIdx.x * blockDim.x + threadIdx.x;
  if (i >= n4) return;
  float4 v = ((const float4*)in)[i];
  ushort4 o;
  o.x = f2bf(v.x); o.y = f2bf(v.y); o.z = f2bf(v.z); o.w = f2bf(v.w);
  ((ushort4*)out)[i] = o;
}

// --------------------------- gates: logits + softmax ------------------------
__global__ __launch_bounds__(256) void gates_k(
    const unsigned short* __restrict__ xb,   // [16384,1024] bf16
    const unsigned short* __restrict__ Wgb,  // [32,1024] bf16
    const float* __restrict__ bg,            // [32]
    float* __restrict__ gw)                  // [16384,32] fp32 softmaxed
{
  const int lane = threadIdx.x & 63;
  const int wid = threadIdx.x >> 6;
  const int wgid = blockIdx.x * 4 + wid;
  const int brow = wgid * 16;
  const int l15 = lane & 15, lhi = lane >> 4;

  f32x4 acc0 = {0.f, 0.f, 0.f, 0.f};
  f32x4 acc1 = {0.f, 0.f, 0.f, 0.f};
  for (int k0 = 0; k0 < 1024; k0 += 32) {
    bf16x8 a  = *(const bf16x8*)&xb[(size_t)(brow + l15) * 1024 + k0 + lhi * 8];
    bf16x8 b0 = *(const bf16x8*)&Wgb[(size_t)l15 * 1024 + k0 + lhi * 8];
    bf16x8 b1 = *(const bf16x8*)&Wgb[(size_t)(16 + l15) * 1024 + k0 + lhi * 8];
    acc0 = __builtin_amdgcn_mfma_f32_16x16x32_bf16(a, b0, acc0, 0, 0, 0);
    acc1 = __builtin_amdgcn_mfma_f32_16x16x32_bf16(a, b1, acc1, 0, 0, 0);
  }
  const float bg0 = bg[l15];
  const float bg1 = bg[16 + l15];
#pragma unroll
  for (int r = 0; r < 4; ++r) {
    float v0 = acc0[r] + bg0;
    float v1 = acc1[r] + bg1;
    float m0 = v0, m1 = v1;
#pragma unroll
    for (int d = 1; d <= 4; d <<= 1) {
      m0 = fmaxf(m0, __shfl_xor(m0, d));
      m1 = fmaxf(m1, __shfl_xor(m1, d));
    }
    float e0 = __expf(v0 - m0), e1 = __expf(v1 - m1);
    float s0 = e0, s1 = e1;
#pragma unroll
    for (int d = 1; d <= 4; d <<= 1) {
      s0 += __shfl_xor(s0, d);
      s1 += __shfl_xor(s1, d);
    }
    int b = brow + lhi * 4 + r;
    gw[(size_t)b * 32 + l15]      = e0 / s0;
    gw[(size_t)b * 32 + 16 + l15] = e1 / s1;
  }
}

// --------------------------- 256x256 pipelined GEMM (B^T) -------------------
// C[m,n] = relu(sum_k A[m,k]*B[n,k] + bias[n]), bf16 out. 8 waves (2M x 4N),
// per-wave 128x64 output, BK=64, double-buffered 128 KiB LDS.
// Swapped MFMA operands: acc regs hold 4 consecutive columns -> ushort4 store.
template <bool RELU>
__global__ __launch_bounds__(512, 2) void gemm256(
    const unsigned short* __restrict__ A, int lda, int aZ,
    const unsigned short* __restrict__ B,     // [z][N][K]
    const float* __restrict__ bias,           // [z][N]
    unsigned short* __restrict__ C, int ldc, int cZ,
    int tilesN, int N, int K)
{
  extern __shared__ char smem_raw[];
  unsigned short* lds = (unsigned short*)smem_raw;  // 2 buf x 4 regions x 8192 elems

  const int tid = threadIdx.x;
  const int lane = tid & 63, wid = tid >> 6;
  const int wr = wid >> 2, wc = wid & 3;
  const int l15 = lane & 15, lhi = lane >> 4;

  // T1: bijective XCD swizzle (gridDim.x % 8 == 0 in all launches here)
  const int nwg = gridDim.x;
  const int cpx = nwg >> 3;
  const int wg = blockIdx.x;
  const int swz = (wg & 7) * cpx + (wg >> 3);
  const int rt = swz / tilesN, ct = swz - rt * tilesN;
  const int brow = rt * 256, bcol = ct * 256;
  const int e = blockIdx.z;

  const unsigned short* Ab = A + (size_t)e * aZ;
  const unsigned short* Bb = B + (size_t)e * N * K;
  const float* biasb = bias + (size_t)e * N;
  unsigned short* Cb = C + (size_t)e * cZ;

  const int NT = K >> 6;

  // bias vectors (4 consecutive cols per lane, matches acc regs)
  f32x4 bias4[4];
#pragma unroll
  for (int nf = 0; nf < 4; ++nf)
    bias4[nf] = *(const f32x4*)&biasb[bcol + wc * 64 + nf * 16 + lhi * 4];

  const f32x4 zero = {0.f, 0.f, 0.f, 0.f};
  f32x4 acc[8][4];
#pragma unroll
  for (int m = 0; m < 8; ++m)
#pragma unroll
    for (int n = 0; n < 4; ++n) acc[m][n] = zero;

  // prologue: stage K-tiles 0 and 1 (A0,A1,B0,B1 halves each; 8 loads/tile)
#pragma unroll
  for (int tt = 0; tt < 2; ++tt) {
#pragma unroll
    for (int h = 0; h < 2; ++h)
      stage_half(Ab + (size_t)(brow + h * 128) * lda + tt * 64, lda,
                 lds + (tt * 4 + h) * 8192, wid, lane);
#pragma unroll
    for (int h = 0; h < 2; ++h)
      stage_half(Bb + (size_t)(bcol + h * 128) * K + tt * 64, K,
                 lds + (tt * 4 + 2 + h) * 8192, wid, lane);
  }
  asm volatile("s_waitcnt vmcnt(8)" ::: "memory");  // K-tile 0 landed
  __builtin_amdgcn_s_barrier();

  const int bro = (wc & 1) * 64;  // B row offset within the wave's B region

#pragma unroll 1
  for (int t = 0; t < NT; ++t) {
    const int b = t & 1;
    const unsigned short* Ar = lds + (b * 4 + wr) * 8192;
    const unsigned short* Br = lds + (b * 4 + 2 + (wc >> 1)) * 8192;

    bf16x8 af0[4][2], af1[4][2], bf0[2][2], bf1[2][2];

    // ---- phase 0: read af0(8) + bf0(4); MFMA Q0 ----
#pragma unroll
    for (int m = 0; m < 4; ++m)
#pragma unroll
      for (int kk = 0; kk < 2; ++kk)
        af0[m][kk] = frag_ld(Ar, m * 16 + l15, kk, lhi);
#pragma unroll
    for (int n = 0; n < 2; ++n)
#pragma unroll
      for (int kk = 0; kk < 2; ++kk)
        bf0[n][kk] = frag_ld(Br, bro + n * 16 + l15, kk, lhi);
    __builtin_amdgcn_s_barrier();
    __builtin_amdgcn_s_setprio(1);
#pragma unroll
    for (int m = 0; m < 4; ++m)
#pragma unroll
      for (int n = 0; n < 2; ++n)
#pragma unroll
        for (int kk = 0; kk < 2; ++kk)
          acc[m][n] = __builtin_amdgcn_mfma_f32_16x16x32_bf16(bf0[n][kk], af0[m][kk], acc[m][n], 0, 0, 0);
    __builtin_amdgcn_s_setprio(0);
    __builtin_amdgcn_s_barrier();

    // ---- phase 1: read bf1(4) first, then af1(8); MFMA Q1 (af0 x bf1) ----
#pragma unroll
    for (int n = 0; n < 2; ++n)
#pragma unroll
      for (int kk = 0; kk < 2; ++kk)
        bf1[n][kk] = frag_ld(Br, bro + (2 + n) * 16 + l15, kk, lhi);
#pragma unroll
    for (int m = 0; m < 4; ++m)
#pragma unroll
      for (int kk = 0; kk < 2; ++kk)
        af1[m][kk] = frag_ld(Ar, (4 + m) * 16 + l15, kk, lhi);
    __builtin_amdgcn_s_barrier();
    __builtin_amdgcn_s_setprio(1);
#pragma unroll
    for (int m = 0; m < 4; ++m)
#pragma unroll
      for (int n = 0; n < 2; ++n)
#pragma unroll
        for (int kk = 0; kk < 2; ++kk)
          acc[m][2 + n] = __builtin_amdgcn_mfma_f32_16x16x32_bf16(bf1[n][kk], af0[m][kk], acc[m][2 + n], 0, 0, 0);
    __builtin_amdgcn_s_setprio(0);
    __builtin_amdgcn_s_barrier();

    // ---- phase 2: stage A of K-tile t+2; MFMA Q2 (af1 x bf0) ----
    if (t + 2 < NT) {
      const int kt = t + 2;
#pragma unroll
      for (int h = 0; h < 2; ++h)
        stage_half(Ab + (size_t)(brow + h * 128) * lda + kt * 64, lda,
                   lds + (b * 4 + h) * 8192, wid, lane);
    }
    __builtin_amdgcn_s_barrier();
    __builtin_amdgcn_s_setprio(1);
#pragma unroll
    for (int m = 0; m < 4; ++m)
#pragma unroll
      for (int n = 0; n < 2; ++n)
#pragma unroll
        for (int kk = 0; kk < 2; ++kk)
          acc[4 + m][n] = __builtin_amdgcn_mfma_f32_16x16x32_bf16(bf0[n][kk], af1[m][kk], acc[4 + m][n], 0, 0, 0);
    __builtin_amdgcn_s_setprio(0);
    __builtin_amdgcn_s_barrier();

    // ---- phase 3: stage B of K-tile t+2; MFMA Q3 (af1 x bf1) ----
    if (t + 2 < NT) {
      const int kt = t + 2;
#pragma unroll
      for (int h = 0; h < 2; ++h)
        stage_half(Bb + (size_t)(bcol + h * 128) * K + kt * 64, K,
                   lds + (b * 4 + 2 + h) * 8192, wid, lane);
    }
    __builtin_amdgcn_s_barrier();
    __builtin_amdgcn_s_setprio(1);
#pragma unroll
    for (int m = 0; m < 4; ++m)
#pragma unroll
      for (int n = 0; n < 2; ++n)
#pragma unroll
        for (int kk = 0; kk < 2; ++kk)
          acc[4 + m][2 + n] = __builtin_amdgcn_mfma_f32_16x16x32_bf16(bf1[n][kk], af1[m][kk], acc[4 + m][2 + n], 0, 0, 0);
    __builtin_amdgcn_s_setprio(0);

    // K-tile boundary: counted vmcnt, then barrier (skip after last tile)
    if (t + 2 < NT) {
      asm volatile("s_waitcnt vmcnt(8)" ::: "memory");
      __builtin_amdgcn_s_barrier();
    } else if (t + 1 < NT) {
      asm volatile("s_waitcnt vmcnt(0)" ::: "memory");
      __builtin_amdgcn_s_barrier();
    }
  }

  // epilogue: lane holds rows m (l15), 4 consecutive cols per frag -> ushort4
#pragma unroll
  for (int mf = 0; mf < 8; ++mf) {
    const size_t rowoff = (size_t)(brow + wr * 128 + mf * 16 + l15) * ldc;
#pragma unroll
    for (int nf = 0; nf < 4; ++nf) {
      const int col = bcol + wc * 64 + nf * 16 + lhi * 4;
      f32x4 v = acc[mf][nf];
      ushort4 o;
      float v0 = v[0] + bias4[nf][0];
      float v1 = v[1] + bias4[nf][1];
      float v2 = v[2] + bias4[nf][2];
      float v3 = v[3] + bias4[nf][3];
      if (RELU) {
        v0 = v0 > 0.f ? v0 : 0.f;
        v1 = v1 > 0.f ? v1 : 0.f;
        v2 = v2 > 0.f ? v2 : 0.f;
        v3 = v3 > 0.f ? v3 : 0.f;
      }
      o.x = f2bf(v0); o.y = f2bf(v1); o.z = f2bf(v2); o.w = f2bf(v3);
      *(ushort4*)&Cb[rowoff + col] = o;
    }
  }
}

// --------------------------- weighted combine -------------------------------
__global__ __launch_bounds__(256) void combine_k(
    const unsigned short* __restrict__ feats,  // [16384][8][256] bf16
    const float* __restrict__ gw,              // [16384][4][8]
    float* __restrict__ out)                   // [4][16384][256] fp32
{
  int tid = blockIdx.x * 256 + threadIdx.x;
  int b = tid >> 5;
  int d0 = (tid & 31) * 8;

  const f32x4* wv4 = (const f32x4*)(gw + (size_t)b * 32);
  f32x4 wv[8];
#pragma unroll
  for (int i = 0; i < 8; ++i) wv[i] = wv4[i];

  float o[4][8];
#pragma unroll
  for (int t = 0; t < 4; ++t)
#pragma unroll
    for (int j = 0; j < 8; ++j) o[t][j] = 0.f;

#pragma unroll
  for (int e = 0; e < 8; ++e) {
    u16x8 fv = *(const u16x8*)&feats[((size_t)b * 8 + e) * 256 + d0];
    float f[8];
#pragma unroll
    for (int j = 0; j < 8; ++j) f[j] = bf2f(fv[j]);
#pragma unroll
    for (int t = 0; t < 4; ++t) {
      float wt = wv[(t * 8 + e) >> 2][(t * 8 + e) & 3];
#pragma unroll
      for (int j = 0; j < 8; ++j) o[t][j] += wt * f[j];
    }
  }
#pragma unroll
  for (int t = 0; t < 4; ++t) {
    f32x4* dst = (f32x4*)(out + ((size_t)t * 16384 + b) * 256 + d0);
    f32x4 s0 = {o[t][0], o[t][1], o[t][2], o[t][3]};
    f32x4 s1 = {o[t][4], o[t][5], o[t][6], o[t][7]};
    dst[0] = s0;
    dst[1] = s1;
  }
}

// ---------------------------------------------------------------------------
extern "C" void kernel_launch(void* const* d_in, const int* in_sizes, int n_in,
                              void* d_out, int out_size, void* d_ws, size_t ws_size,
                              hipStream_t stream) {
  (void)in_sizes; (void)n_in; (void)out_size; (void)ws_size;
  const float* x  = (const float*)d_in[0];   // [16384,1024]
  const float* W1 = (const float*)d_in[1];   // [8,512,1024]
  const float* b1 = (const float*)d_in[2];   // [8,512]
  const float* W2 = (const float*)d_in[3];   // [8,256,512]
  const float* b2 = (const float*)d_in[4];   // [8,256]
  const float* Wg = (const float*)d_in[5];   // [4,8,1024]
  const float* bg = (const float*)d_in[6];   // [4,8]
  float* out = (float*)d_out;                // [4,16384,256]

  char* ws = (char*)d_ws;
  unsigned short* xb    = (unsigned short*)ws; ws += (size_t)16384 * 1024 * 2;  // 32 MB
  unsigned short* W1b   = (unsigned short*)ws; ws += (size_t)4096 * 1024 * 2;   // 8 MB
  unsigned short* W2b   = (unsigned short*)ws; ws += (size_t)2048 * 512 * 2;    // 2 MB
  unsigned short* Wgb   = (unsigned short*)ws; ws += (size_t)32 * 1024 * 2;     // 64 KB
  float*          gw    = (float*)ws;         ws += (size_t)16384 * 32 * 4;     // 2 MB
  unsigned short* H     = (unsigned short*)ws; ws += (size_t)16384 * 4096 * 2;  // 128 MB
  unsigned short* feats = (unsigned short*)ws; ws += (size_t)16384 * 2048 * 2;  // 64 MB

  // fp32 -> bf16
  cvt_k<<<16384, 256, 0, stream>>>(x, xb, 16384 * 1024 / 4);
  cvt_k<<<4096, 256, 0, stream>>>(W1, W1b, 4096 * 1024 / 4);
  cvt_k<<<1024, 256, 0, stream>>>(W2, W2b, 2048 * 512 / 4);
  cvt_k<<<32, 256, 0, stream>>>(Wg, Wgb, 32 * 1024 / 4);

  // gates: logits + softmax -> gw
  gates_k<<<256, 256, 0, stream>>>(xb, Wgb, bg, gw);

  // layer1: H = relu(xb @ W1^T + b1), M=16384 N=4096 K=1024 -> 64x16=1024 wgs
  gemm256<true><<<dim3(1024, 1, 1), 512, 131072, stream>>>(
      xb, 1024, 0, W1b, b1, H, 4096, 0, /*tilesN*/16, 4096, 1024);

  // layer2 (batched over experts): feats[:,e,:] = relu(H[:,e*512:+512] @ W2[e]^T + b2[e])
  gemm256<true><<<dim3(64, 1, 8), 512, 131072, stream>>>(
      H, 4096, 512, W2b, b2, feats, 2048, 256, /*tilesN*/1, 256, 512);

  // combine: out[t,b,d] = sum_e feats[b,e,d] * gw[b,t,e]
  combine_k<<<2048, 256, 0, stream>>>(feats, gw, out);
}

// Round 3
// 278.631 us; speedup vs baseline: 1.5032x; 1.5032x over previous
//
#include <hip/hip_runtime.h>

// ---------------------------------------------------------------------------
// Multi-gate MoE: x[16384,1024] -> experts (2x Linear+ReLU, E=8) -> 4 gates.
// GEMM: 256x256 tile, 8 waves (2Mx4N), BK=64, 8-phase (4/K-tile) pipelined
// schedule per m201 discipline:
//   - T2 granule swizzle (conflict-free ds_read_b128, pre-swizzled gsrc)
//   - 2 global_load_lds per thread per phase, rolling 1-tile-ahead prefetch
//   - derived counted waits: vmcnt(4) @ end-P2, vmcnt(2) @ end-P4 (never 0)
//   - kk-outer MFMA (dep distance 8), T5 setprio, T1 XCD swizzle
// ---------------------------------------------------------------------------

typedef __attribute__((ext_vector_type(8))) __bf16 bf16x8;
typedef __attribute__((ext_vector_type(4))) float f32x4;
typedef __attribute__((ext_vector_type(8))) unsigned short u16x8;

__device__ __forceinline__ float bf2f(unsigned short u) {
  union { unsigned int i; float f; } x;
  x.i = ((unsigned int)u) << 16;
  return x.f;
}

__device__ __forceinline__ unsigned short f2bf(float f) {
  union { float f; unsigned int i; } x;
  x.f = f;
  unsigned int r = x.i + 0x7FFFu + ((x.i >> 16) & 1u);  // round-to-nearest-even
  return (unsigned short)(r >> 16);
}

__device__ __forceinline__ void gload_lds16(const unsigned short* g, unsigned short* l) {
  __builtin_amdgcn_global_load_lds(
      (const __attribute__((address_space(1))) void*)g,
      (__attribute__((address_space(3))) void*)l, 16, 0, 0);
}

// --------------------------- fp32 -> bf16 convert ---------------------------
__global__ void cvt_k(const float* __restrict__ in, unsigned short* __restrict__ out, int n4) {
  int i = blockIdx.x * blockDim.x + threadIdx.x;
  if (i >= n4) return;
  float4 v = ((const float4*)in)[i];
  ushort4 o;
  o.x = f2bf(v.x); o.y = f2bf(v.y); o.z = f2bf(v.z); o.w = f2bf(v.w);
  ((ushort4*)out)[i] = o;
}

// --------------------------- gates: logits + softmax ------------------------
__global__ __launch_bounds__(256) void gates_k(
    const unsigned short* __restrict__ xb,   // [16384,1024] bf16
    const unsigned short* __restrict__ Wgb,  // [32,1024] bf16
    const float* __restrict__ bg,            // [32]
    float* __restrict__ gw)                  // [16384,32] fp32 softmaxed
{
  const int lane = threadIdx.x & 63;
  const int wid = threadIdx.x >> 6;
  const int wgid = blockIdx.x * 4 + wid;
  const int brow = wgid * 16;
  const int l15 = lane & 15, lhi = lane >> 4;

  f32x4 acc0 = {0.f, 0.f, 0.f, 0.f};
  f32x4 acc1 = {0.f, 0.f, 0.f, 0.f};
  for (int k0 = 0; k0 < 1024; k0 += 32) {
    bf16x8 a  = *(const bf16x8*)&xb[(size_t)(brow + l15) * 1024 + k0 + lhi * 8];
    bf16x8 b0 = *(const bf16x8*)&Wgb[(size_t)l15 * 1024 + k0 + lhi * 8];
    bf16x8 b1 = *(const bf16x8*)&Wgb[(size_t)(16 + l15) * 1024 + k0 + lhi * 8];
    acc0 = __builtin_amdgcn_mfma_f32_16x16x32_bf16(a, b0, acc0, 0, 0, 0);
    acc1 = __builtin_amdgcn_mfma_f32_16x16x32_bf16(a, b1, acc1, 0, 0, 0);
  }
  const float bg0 = bg[l15];
  const float bg1 = bg[16 + l15];
#pragma unroll
  for (int r = 0; r < 4; ++r) {
    float v0 = acc0[r] + bg0;
    float v1 = acc1[r] + bg1;
    float m0 = v0, m1 = v1;
#pragma unroll
    for (int d = 1; d <= 4; d <<= 1) {
      m0 = fmaxf(m0, __shfl_xor(m0, d));
      m1 = fmaxf(m1, __shfl_xor(m1, d));
    }
    float e0 = __expf(v0 - m0), e1 = __expf(v1 - m1);
    float s0 = e0, s1 = e1;
#pragma unroll
    for (int d = 1; d <= 4; d <<= 1) {
      s0 += __shfl_xor(s0, d);
      s1 += __shfl_xor(s1, d);
    }
    int b = brow + lhi * 4 + r;
    gw[(size_t)b * 32 + l15]      = e0 / s0;
    gw[(size_t)b * 32 + 16 + l15] = e1 / s1;
  }
}

// --------------------------- 256x256 pipelined GEMM (B^T) -------------------
// LDS (bytes): A slot s @ s*32768 (256 rows x 64 cols bf16, 128 B/row,
// granule-swizzled g_phys = g_log ^ (row&7)); B slot s @ 65536 + s*32768.
// Stage unit = 64 rows (8 KB) = 1 load/thread.
template <bool RELU>
__global__ __launch_bounds__(512, 2) void gemm256(
    const unsigned short* __restrict__ A, int lda, int aZ,
    const unsigned short* __restrict__ B,     // [z][N][K]
    const float* __restrict__ bias,           // [z][N]
    unsigned short* __restrict__ C, int ldc, int cZ,
    int tilesN, int N, int K)
{
  extern __shared__ char smem_raw[];
  unsigned short* lds = (unsigned short*)smem_raw;
  char* ldsb = (char*)smem_raw;

  const int tid = threadIdx.x;
  const int lane = tid & 63, wid = tid >> 6;
  const int wr = wid >> 2, wc = wid & 3;
  const int l15 = lane & 15, lhi = lane >> 4;

  // T1: bijective XCD swizzle (gridDim.x % 8 == 0 in all launches here)
  const int nwg = gridDim.x;
  const int cpx = nwg >> 3;
  const int wg = blockIdx.x;
  const int swz = (wg & 7) * cpx + (wg >> 3);
  const int rt = swz / tilesN, ct = swz - rt * tilesN;
  const int brow = rt * 256, bcol = ct * 256;
  const int e = blockIdx.z;

  const unsigned short* Ab = A + (size_t)e * aZ + (size_t)brow * lda;
  const unsigned short* Bb = B + (size_t)e * N * K + (size_t)bcol * K;
  const float* biasb = bias + (size_t)e * N;
  unsigned short* Cb = C + (size_t)e * cZ;

  const int NT = K >> 6;
  const int NI = NT >> 1;

  // staging per-thread constants (unit = 64 rows x 64 cols)
  const int trow = tid >> 3;                          // row within unit
  const int cg8 = (((tid & 7) ^ (trow & 7)) << 3);    // swizzled src col (elems)

  // ds_read per-thread constants: addr = base + (row<<7) + ((kcol) ^ ((row&7)<<4))
  // row = <mult of 8> + l15  ->  row&7 == l15&7 (thread-constant)
  const int axor = (l15 & 7) << 4;
  const int koff0 = (lhi << 4) ^ axor;
  const int koff1 = (64 + (lhi << 4)) ^ axor;

  const char* pA0 = ldsb + wr * 16384 + l15 * 128 + koff0;
  const char* pA1 = ldsb + wr * 16384 + l15 * 128 + koff1;
  const char* pB0 = ldsb + 65536 + wc * 8192 + l15 * 128 + koff0;
  const char* pB1 = ldsb + 65536 + wc * 8192 + l15 * 128 + koff1;

  // bias vectors (4 consecutive cols per lane, matches acc regs)
  f32x4 bias4[4];
#pragma unroll
  for (int nf = 0; nf < 4; ++nf)
    bias4[nf] = *(const f32x4*)&biasb[bcol + wc * 64 + nf * 16 + lhi * 4];

  const f32x4 zero = {0.f, 0.f, 0.f, 0.f};
  f32x4 acc[8][4];
#pragma unroll
  for (int m = 0; m < 8; ++m)
#pragma unroll
    for (int n = 0; n < 4; ++n) acc[m][n] = zero;

  auto STAGE_A = [&](int slot, int t, int u) {
    gload_lds16(Ab + (size_t)(u * 64 + trow) * lda + (t * 64 + cg8),
                lds + slot * 16384 + u * 4096 + wid * 512);
  };
  auto STAGE_B = [&](int slot, int t, int u) {
    gload_lds16(Bb + (size_t)(u * 64 + trow) * K + (t * 64 + cg8),
                lds + 32768 + slot * 16384 + u * 4096 + wid * 512);
  };

  // prologue: stage K-tile 0 into slot 0, full drain once
#pragma unroll
  for (int u = 0; u < 4; ++u) STAGE_B(0, 0, u);
#pragma unroll
  for (int u = 0; u < 4; ++u) STAGE_A(0, 0, u);
  asm volatile("s_waitcnt vmcnt(0)" ::: "memory");
  __builtin_amdgcn_s_barrier();

  // one K-tile = 4 phases; stages target slot^1 / K-tile tn.
  auto ktile = [&](int slot, int tn, bool stageNext) {
    bf16x8 af[4][2], bfr[4][2];
    // ---- P1: read af m0-3 (8) + bf n0-1 (4); stage B u0,u1; MFMA QA
#pragma unroll
    for (int mi = 0; mi < 4; ++mi) {
      af[mi][0] = *(const bf16x8*)(pA0 + slot * 32768 + mi * 2048);
      af[mi][1] = *(const bf16x8*)(pA1 + slot * 32768 + mi * 2048);
    }
#pragma unroll
    for (int n = 0; n < 2; ++n) {
      bfr[n][0] = *(const bf16x8*)(pB0 + slot * 32768 + n * 2048);
      bfr[n][1] = *(const bf16x8*)(pB1 + slot * 32768 + n * 2048);
    }
    if (stageNext) { STAGE_B(slot ^ 1, tn, 0); STAGE_B(slot ^ 1, tn, 1); }
    __builtin_amdgcn_s_barrier();
    __builtin_amdgcn_s_setprio(1);
#pragma unroll
    for (int kk = 0; kk < 2; ++kk)
#pragma unroll
      for (int mi = 0; mi < 4; ++mi)
#pragma unroll
        for (int n = 0; n < 2; ++n)
          acc[mi][n] = __builtin_amdgcn_mfma_f32_16x16x32_bf16(bfr[n][kk], af[mi][kk], acc[mi][n], 0, 0, 0);
    __builtin_amdgcn_s_setprio(0);
    __builtin_amdgcn_s_barrier();

    // ---- P2: read bf n2-3 (4); stage B u2,u3; MFMA QB; vmcnt(4)
#pragma unroll
    for (int n = 0; n < 2; ++n) {
      bfr[2 + n][0] = *(const bf16x8*)(pB0 + slot * 32768 + (2 + n) * 2048);
      bfr[2 + n][1] = *(const bf16x8*)(pB1 + slot * 32768 + (2 + n) * 2048);
    }
    if (stageNext) { STAGE_B(slot ^ 1, tn, 2); STAGE_B(slot ^ 1, tn, 3); }
    __builtin_amdgcn_s_barrier();
    __builtin_amdgcn_s_setprio(1);
#pragma unroll
    for (int kk = 0; kk < 2; ++kk)
#pragma unroll
      for (int mi = 0; mi < 4; ++mi)
#pragma unroll
        for (int n = 0; n < 2; ++n)
          acc[mi][2 + n] = __builtin_amdgcn_mfma_f32_16x16x32_bf16(bfr[2 + n][kk], af[mi][kk], acc[mi][2 + n], 0, 0, 0);
    __builtin_amdgcn_s_setprio(0);
    asm volatile("s_waitcnt vmcnt(4)" ::: "memory");  // prev K-tile's A u1,u3 landed
    __builtin_amdgcn_s_barrier();

    // ---- P3: read af m4-7 (8); stage A u0,u2; MFMA QC (bf reused)
#pragma unroll
    for (int mi = 0; mi < 4; ++mi) {
      af[mi][0] = *(const bf16x8*)(pA0 + slot * 32768 + 8192 + mi * 2048);
      af[mi][1] = *(const bf16x8*)(pA1 + slot * 32768 + 8192 + mi * 2048);
    }
    if (stageNext) { STAGE_A(slot ^ 1, tn, 0); STAGE_A(slot ^ 1, tn, 2); }
    __builtin_amdgcn_s_barrier();
    __builtin_amdgcn_s_setprio(1);
#pragma unroll
    for (int kk = 0; kk < 2; ++kk)
#pragma unroll
      for (int mi = 0; mi < 4; ++mi)
#pragma unroll
        for (int n = 0; n < 2; ++n)
          acc[4 + mi][n] = __builtin_amdgcn_mfma_f32_16x16x32_bf16(bfr[n][kk], af[mi][kk], acc[4 + mi][n], 0, 0, 0);
    __builtin_amdgcn_s_setprio(0);
    __builtin_amdgcn_s_barrier();

    // ---- P4: stage A u1,u3; MFMA QD; vmcnt(2) (this tile's B + A u0,u2 landed)
    if (stageNext) { STAGE_A(slot ^ 1, tn, 1); STAGE_A(slot ^ 1, tn, 3); }
    __builtin_amdgcn_s_barrier();
    __builtin_amdgcn_s_setprio(1);
#pragma unroll
    for (int kk = 0; kk < 2; ++kk)
#pragma unroll
      for (int mi = 0; mi < 4; ++mi)
#pragma unroll
        for (int n = 0; n < 2; ++n)
          acc[4 + mi][2 + n] = __builtin_amdgcn_mfma_f32_16x16x32_bf16(bfr[2 + n][kk], af[mi][kk], acc[4 + mi][2 + n], 0, 0, 0);
    __builtin_amdgcn_s_setprio(0);
    asm volatile("s_waitcnt vmcnt(2)" ::: "memory");
    __builtin_amdgcn_s_barrier();
  };

  for (int i = 0; i < NI; ++i) {
    ktile(0, 2 * i + 1, true);
    ktile(1, 2 * i + 2, (2 * i + 2) < NT);
  }

  // epilogue: lane holds 4 consecutive cols per frag -> ushort4 store
#pragma unroll
  for (int mf = 0; mf < 8; ++mf) {
    const size_t rowoff = (size_t)(brow + wr * 128 + mf * 16 + l15) * ldc;
#pragma unroll
    for (int nf = 0; nf < 4; ++nf) {
      const int col = bcol + wc * 64 + nf * 16 + lhi * 4;
      f32x4 v = acc[mf][nf];
      ushort4 o;
      float v0 = v[0] + bias4[nf][0];
      float v1 = v[1] + bias4[nf][1];
      float v2 = v[2] + bias4[nf][2];
      float v3 = v[3] + bias4[nf][3];
      if (RELU) {
        v0 = v0 > 0.f ? v0 : 0.f;
        v1 = v1 > 0.f ? v1 : 0.f;
        v2 = v2 > 0.f ? v2 : 0.f;
        v3 = v3 > 0.f ? v3 : 0.f;
      }
      o.x = f2bf(v0); o.y = f2bf(v1); o.z = f2bf(v2); o.w = f2bf(v3);
      *(ushort4*)&Cb[rowoff + col] = o;
    }
  }
}

// --------------------------- weighted combine -------------------------------
__global__ __launch_bounds__(256) void combine_k(
    const unsigned short* __restrict__ feats,  // [16384][8][256] bf16
    const float* __restrict__ gw,              // [16384][4][8]
    float* __restrict__ out)                   // [4][16384][256] fp32
{
  int tid = blockIdx.x * 256 + threadIdx.x;
  int b = tid >> 5;
  int d0 = (tid & 31) * 8;

  const f32x4* wv4 = (const f32x4*)(gw + (size_t)b * 32);
  f32x4 wv[8];
#pragma unroll
  for (int i = 0; i < 8; ++i) wv[i] = wv4[i];

  float o[4][8];
#pragma unroll
  for (int t = 0; t < 4; ++t)
#pragma unroll
    for (int j = 0; j < 8; ++j) o[t][j] = 0.f;

#pragma unroll
  for (int e = 0; e < 8; ++e) {
    u16x8 fv = *(const u16x8*)&feats[((size_t)b * 8 + e) * 256 + d0];
    float f[8];
#pragma unroll
    for (int j = 0; j < 8; ++j) f[j] = bf2f(fv[j]);
#pragma unroll
    for (int t = 0; t < 4; ++t) {
      float wt = wv[(t * 8 + e) >> 2][(t * 8 + e) & 3];
#pragma unroll
      for (int j = 0; j < 8; ++j) o[t][j] += wt * f[j];
    }
  }
#pragma unroll
  for (int t = 0; t < 4; ++t) {
    f32x4* dst = (f32x4*)(out + ((size_t)t * 16384 + b) * 256 + d0);
    f32x4 s0 = {o[t][0], o[t][1], o[t][2], o[t][3]};
    f32x4 s1 = {o[t][4], o[t][5], o[t][6], o[t][7]};
    dst[0] = s0;
    dst[1] = s1;
  }
}

// ---------------------------------------------------------------------------
extern "C" void kernel_launch(void* const* d_in, const int* in_sizes, int n_in,
                              void* d_out, int out_size, void* d_ws, size_t ws_size,
                              hipStream_t stream) {
  (void)in_sizes; (void)n_in; (void)out_size; (void)ws_size;
  const float* x  = (const float*)d_in[0];   // [16384,1024]
  const float* W1 = (const float*)d_in[1];   // [8,512,1024]
  const float* b1 = (const float*)d_in[2];   // [8,512]
  const float* W2 = (const float*)d_in[3];   // [8,256,512]
  const float* b2 = (const float*)d_in[4];   // [8,256]
  const float* Wg = (const float*)d_in[5];   // [4,8,1024]
  const float* bg = (const float*)d_in[6];   // [4,8]
  float* out = (float*)d_out;                // [4,16384,256]

  char* ws = (char*)d_ws;
  unsigned short* xb    = (unsigned short*)ws; ws += (size_t)16384 * 1024 * 2;  // 32 MB
  unsigned short* W1b   = (unsigned short*)ws; ws += (size_t)4096 * 1024 * 2;   // 8 MB
  unsigned short* W2b   = (unsigned short*)ws; ws += (size_t)2048 * 512 * 2;    // 2 MB
  unsigned short* Wgb   = (unsigned short*)ws; ws += (size_t)32 * 1024 * 2;     // 64 KB
  float*          gw    = (float*)ws;         ws += (size_t)16384 * 32 * 4;     // 2 MB
  unsigned short* H     = (unsigned short*)ws; ws += (size_t)16384 * 4096 * 2;  // 128 MB
  unsigned short* feats = (unsigned short*)ws; ws += (size_t)16384 * 2048 * 2;  // 64 MB

  // fp32 -> bf16
  cvt_k<<<16384, 256, 0, stream>>>(x, xb, 16384 * 1024 / 4);
  cvt_k<<<4096, 256, 0, stream>>>(W1, W1b, 4096 * 1024 / 4);
  cvt_k<<<1024, 256, 0, stream>>>(W2, W2b, 2048 * 512 / 4);
  cvt_k<<<32, 256, 0, stream>>>(Wg, Wgb, 32 * 1024 / 4);

  // gates: logits + softmax -> gw
  gates_k<<<256, 256, 0, stream>>>(xb, Wgb, bg, gw);

  // layer1: H = relu(xb @ W1^T + b1), M=16384 N=4096 K=1024 -> 64x16=1024 wgs
  gemm256<true><<<dim3(1024, 1, 1), 512, 131072, stream>>>(
      xb, 1024, 0, W1b, b1, H, 4096, 0, /*tilesN*/16, 4096, 1024);

  // layer2 (batched over experts): feats[:,e,:] = relu(H[:,e*512:+512] @ W2[e]^T + b2[e])
  gemm256<true><<<dim3(64, 1, 8), 512, 131072, stream>>>(
      H, 4096, 512, W2b, b2, feats, 2048, 256, /*tilesN*/1, 256, 512);

  // combine: out[t,b,d] = sum_e feats[b,e,d] * gw[b,t,e]
  combine_k<<<2048, 256, 0, stream>>>(feats, gw, out);
}